// Round 1
// baseline (897.028 us; speedup 1.0000x reference)
//
#include <hip/hip_runtime.h>

#define N_PTS 1000000
#define RANK 64
#define DC 128
#define DF 512

typedef __attribute__((ext_vector_type(8))) short short8;
typedef __attribute__((ext_vector_type(4))) float f32x4;
typedef __attribute__((ext_vector_type(2))) float f32x2;

__device__ __forceinline__ unsigned short f2bf(float f) {
  unsigned int u = __float_as_uint(f);
  u += 0x7FFFu + ((u >> 16) & 1u);   // round-to-nearest-even
  return (unsigned short)(u >> 16);
}

__device__ __forceinline__ float readlane_f(float v, int l) {
  return __uint_as_float(__builtin_amdgcn_readlane(__float_as_uint(v), l));
}

// dst[a][d][r] = { src[a][r][d], src[a][r][min(d+1,D-1)] }   (paired-transpose)
__global__ void build_pairs(const float* __restrict__ src, f32x2* __restrict__ dst, int D) {
  int tid = blockIdx.x * blockDim.x + threadIdx.x;
  if (tid >= 3 * D * RANK) return;
  int r = tid & (RANK - 1);
  int d = (tid >> 6) & (D - 1);          // D is a power of two
  int a = tid / (D * RANK);
  const float* s = src + (a * RANK + r) * D;
  int d1 = (d + 1 < D) ? d + 1 : D - 1;
  f32x2 v;
  v.x = s[d];
  v.y = s[d1];
  dst[tid] = v;
}

__global__ __launch_bounds__(256) void tensorcp_main(
    const float* __restrict__ xyz,
    const f32x2* __restrict__ CP,   // [3][DC][RANK] pairs
    const f32x2* __restrict__ FP,   // [3][DF][RANK] pairs
    const f32x2* __restrict__ UP,   // [3][DC][RANK] pairs
    const float* __restrict__ Wc,   // [64][64]
    const float* __restrict__ Wf,   // [64][64]
    float* __restrict__ out)        // [N][128] cat ++ [N] uncertainty
{
  __shared__ __align__(16) unsigned short FcS[4][64][72];
  __shared__ __align__(16) unsigned short FfS[4][64][72];

  const int lane = threadIdx.x & 63;
  const int wv = threadIdx.x >> 6;
  const int batch = blockIdx.x * 4 + wv;
  if (batch * 64 >= N_PTS) return;          // wave-uniform exit, no barriers used
  const int p0 = batch * 64;

  const int fcol = lane & 15;
  const int kg = lane >> 4;

  // ---------------- per-lane point parameters ----------------
  const int myp = p0 + lane;
  const float px = xyz[myp * 3 + 0];
  const float py = xyz[myp * 3 + 1];
  const float pz = xyz[myp * 3 + 2];

  float pc0 = px * (float)(DC - 1), pc1 = py * (float)(DC - 1), pc2 = pz * (float)(DC - 1);
  float pf0 = px * (float)(DF - 1), pf1 = py * (float)(DF - 1), pf2 = pz * (float)(DF - 1);
  int ic0 = min(max((int)floorf(pc0), 0), DC - 1);
  int ic1 = min(max((int)floorf(pc1), 0), DC - 1);
  int ic2 = min(max((int)floorf(pc2), 0), DC - 1);
  int if0 = min(max((int)floorf(pf0), 0), DF - 1);
  int if1 = min(max((int)floorf(pf1), 0), DF - 1);
  int if2 = min(max((int)floorf(pf2), 0), DF - 1);
  float wc0 = pc0 - (float)ic0, wc1 = pc1 - (float)ic1, wc2 = pc2 - (float)ic2;
  float wf0 = pf0 - (float)if0, wf1 = pf1 - (float)if1, wf2 = pf2 - (float)if2;

  // ---------------- W fragments (B operand), bf16 in VGPRs ----------------
  // B frag for tile (k,n): lane holds W[n*16+fcol][k*32+kg*8 + j], j=0..7
  short8 Bc[8], Bf[8];   // index = k*4 + n
#pragma unroll
  for (int k = 0; k < 2; ++k) {
#pragma unroll
    for (int n = 0; n < 4; ++n) {
      const float* wp = Wc + (n * 16 + fcol) * 64 + k * 32 + kg * 8;
      f32x4 lo = *(const f32x4*)wp;
      f32x4 hi = *(const f32x4*)(wp + 4);
      short8 b;
      b[0] = (short)f2bf(lo[0]); b[1] = (short)f2bf(lo[1]);
      b[2] = (short)f2bf(lo[2]); b[3] = (short)f2bf(lo[3]);
      b[4] = (short)f2bf(hi[0]); b[5] = (short)f2bf(hi[1]);
      b[6] = (short)f2bf(hi[2]); b[7] = (short)f2bf(hi[3]);
      Bc[k * 4 + n] = b;
      const float* wp2 = Wf + (n * 16 + fcol) * 64 + k * 32 + kg * 8;
      f32x4 lo2 = *(const f32x4*)wp2;
      f32x4 hi2 = *(const f32x4*)(wp2 + 4);
      short8 b2;
      b2[0] = (short)f2bf(lo2[0]); b2[1] = (short)f2bf(lo2[1]);
      b2[2] = (short)f2bf(lo2[2]); b2[3] = (short)f2bf(lo2[3]);
      b2[4] = (short)f2bf(hi2[0]); b2[5] = (short)f2bf(hi2[1]);
      b2[6] = (short)f2bf(hi2[2]); b2[7] = (short)f2bf(hi2[3]);
      Bf[k * 4 + n] = b2;
    }
  }

  // ---------------- feature staging: lane = rank, loop over 64 points ----------------
  unsigned short (&myFc)[64][72] = FcS[wv];
  unsigned short (&myFf)[64][72] = FfS[wv];

  const f32x2* CPx = CP;
  const f32x2* CPy = CP + DC * RANK;
  const f32x2* CPz = CP + 2 * DC * RANK;
  const f32x2* FPx = FP;
  const f32x2* FPy = FP + DF * RANK;
  const f32x2* FPz = FP + 2 * DF * RANK;
  const f32x2* UPx = UP;
  const f32x2* UPy = UP + DC * RANK;
  const f32x2* UPz = UP + 2 * DC * RANK;

  float u_keep = 0.0f;

#pragma unroll 2
  for (int p = 0; p < 64; ++p) {
    const int s_ic0 = __builtin_amdgcn_readlane(ic0, p);
    const int s_ic1 = __builtin_amdgcn_readlane(ic1, p);
    const int s_ic2 = __builtin_amdgcn_readlane(ic2, p);
    const int s_if0 = __builtin_amdgcn_readlane(if0, p);
    const int s_if1 = __builtin_amdgcn_readlane(if1, p);
    const int s_if2 = __builtin_amdgcn_readlane(if2, p);
    const float s_wc0 = readlane_f(wc0, p);
    const float s_wc1 = readlane_f(wc1, p);
    const float s_wc2 = readlane_f(wc2, p);
    const float s_wf0 = readlane_f(wf0, p);
    const float s_wf1 = readlane_f(wf1, p);
    const float s_wf2 = readlane_f(wf2, p);

    const f32x2 c0 = CPx[s_ic0 * RANK + lane];
    const f32x2 c1 = CPy[s_ic1 * RANK + lane];
    const f32x2 c2 = CPz[s_ic2 * RANK + lane];
    const f32x2 g0 = FPx[s_if0 * RANK + lane];
    const f32x2 g1 = FPy[s_if1 * RANK + lane];
    const f32x2 g2 = FPz[s_if2 * RANK + lane];
    const f32x2 u0 = UPx[s_ic0 * RANK + lane];
    const f32x2 u1 = UPy[s_ic1 * RANK + lane];
    const f32x2 u2 = UPz[s_ic2 * RANK + lane];

    const float a0v = fmaf(s_wc0, c0.y - c0.x, c0.x);
    const float a1v = fmaf(s_wc1, c1.y - c1.x, c1.x);
    const float a2v = fmaf(s_wc2, c2.y - c2.x, c2.x);
    const float b0v = fmaf(s_wf0, g0.y - g0.x, g0.x);
    const float b1v = fmaf(s_wf1, g1.y - g1.x, g1.x);
    const float b2v = fmaf(s_wf2, g2.y - g2.x, g2.x);
    const float q0v = fmaf(s_wc0, u0.y - u0.x, u0.x);
    const float q1v = fmaf(s_wc1, u1.y - u1.x, u1.x);
    const float q2v = fmaf(s_wc2, u2.y - u2.x, u2.x);

    const float fc = a0v * a1v * a2v;
    const float ff = b0v * b1v * b2v;
    const float fu = q0v * q1v * q2v;

    myFc[p][lane] = f2bf(fc);
    myFf[p][lane] = f2bf(ff);

    float ssum = fu;
    ssum += __shfl_xor(ssum, 32, 64);
    ssum += __shfl_xor(ssum, 16, 64);
    ssum += __shfl_xor(ssum, 8, 64);
    ssum += __shfl_xor(ssum, 4, 64);
    ssum += __shfl_xor(ssum, 2, 64);
    ssum += __shfl_xor(ssum, 1, 64);
    if (lane == p) u_keep = ssum;
  }

  // drain all LDS writes / shuffles of this wave before reading fragments
  asm volatile("s_waitcnt lgkmcnt(0)" ::: "memory");

  // ---------------- MFMA: Out(64pt x 64f) = F(64x64) * W^T(64x64) ----------------
  const long long rowbase = (long long)p0 * 128;
#pragma unroll
  for (int m = 0; m < 4; ++m) {
    const int prow = m * 16 + fcol;
    const short8 a0 = *(const short8*)&myFc[prow][kg * 8];
    const short8 a1 = *(const short8*)&myFc[prow][32 + kg * 8];
    f32x4 accc[4];
#pragma unroll
    for (int n = 0; n < 4; ++n) {
      f32x4 z = {0.f, 0.f, 0.f, 0.f};
      z = __builtin_amdgcn_mfma_f32_16x16x32_bf16(a0, Bc[n], z, 0, 0, 0);
      z = __builtin_amdgcn_mfma_f32_16x16x32_bf16(a1, Bc[4 + n], z, 0, 0, 0);
      accc[n] = z;
    }
    const short8 e0 = *(const short8*)&myFf[prow][kg * 8];
    const short8 e1 = *(const short8*)&myFf[prow][32 + kg * 8];
    f32x4 accf[4];
#pragma unroll
    for (int n = 0; n < 4; ++n) {
      f32x4 z = {0.f, 0.f, 0.f, 0.f};
      z = __builtin_amdgcn_mfma_f32_16x16x32_bf16(e0, Bf[n], z, 0, 0, 0);
      z = __builtin_amdgcn_mfma_f32_16x16x32_bf16(e1, Bf[4 + n], z, 0, 0, 0);
      accf[n] = z;
    }
#pragma unroll
    for (int reg = 0; reg < 4; ++reg) {
      const long long ro = rowbase + (long long)(m * 16 + kg * 4 + reg) * 128;
#pragma unroll
      for (int n = 0; n < 4; ++n) {
        __builtin_nontemporal_store(accc[n][reg], &out[ro + n * 16 + fcol]);
        __builtin_nontemporal_store(accf[n][reg], &out[ro + 64 + n * 16 + fcol]);
      }
    }
  }

  __builtin_nontemporal_store(u_keep, &out[(long long)N_PTS * 128 + p0 + lane]);
}

extern "C" void kernel_launch(void* const* d_in, const int* in_sizes, int n_in,
                              void* d_out, int out_size, void* d_ws, size_t ws_size,
                              hipStream_t stream) {
  const float* xyz    = (const float*)d_in[0];
  const float* line_c = (const float*)d_in[1];
  const float* line_f = (const float*)d_in[2];
  const float* unc_l  = (const float*)d_in[3];
  const float* Wc     = (const float*)d_in[4];
  const float* Wf     = (const float*)d_in[5];
  float* out = (float*)d_out;

  f32x2* CP = (f32x2*)d_ws;            // 3*128*64 pairs
  f32x2* FP = CP + 3 * DC * RANK;      // 3*512*64 pairs
  f32x2* UP = FP + 3 * DF * RANK;      // 3*128*64 pairs

  const int tc = 3 * DC * RANK;  // 24576
  const int tf = 3 * DF * RANK;  // 98304
  build_pairs<<<(tc + 255) / 256, 256, 0, stream>>>(line_c, CP, DC);
  build_pairs<<<(tf + 255) / 256, 256, 0, stream>>>(line_f, FP, DF);
  build_pairs<<<(tc + 255) / 256, 256, 0, stream>>>(unc_l, UP, DC);

  const int nwaves = N_PTS / 64;            // 15625
  const int nblocks = (nwaves + 3) / 4;     // 3907
  tensorcp_main<<<nblocks, 256, 0, stream>>>(xyz, CP, FP, UP, Wc, Wf, out);
}

// Round 2
// 831.111 us; speedup vs baseline: 1.0793x; 1.0793x over previous
//
#include <hip/hip_runtime.h>

#define N_PTS 1000000
#define RANK 64
#define DC 128
#define DF 512

typedef __attribute__((ext_vector_type(8))) short short8;
typedef __attribute__((ext_vector_type(4))) float f32x4;
typedef __attribute__((ext_vector_type(2))) float f32x2;

__device__ __forceinline__ unsigned short f2bf(float f) {
  unsigned int u = __float_as_uint(f);
  u += 0x7FFFu + ((u >> 16) & 1u);   // round-to-nearest-even
  return (unsigned short)(u >> 16);
}

__device__ __forceinline__ float bf2f(unsigned short s) {
  return __uint_as_float(((unsigned int)s) << 16);
}

__device__ __forceinline__ float readlane_f(float v, int l) {
  return __uint_as_float(__builtin_amdgcn_readlane(__float_as_uint(v), l));
}

// dst[a][d][r] = { src[a][r][d], src[a][r][min(d+1,D-1)] }   (paired-transpose)
__global__ void build_pairs(const float* __restrict__ src, f32x2* __restrict__ dst, int D) {
  int tid = blockIdx.x * blockDim.x + threadIdx.x;
  if (tid >= 3 * D * RANK) return;
  int r = tid & (RANK - 1);
  int d = (tid >> 6) & (D - 1);          // D is a power of two
  int a = tid / (D * RANK);
  const float* s = src + (a * RANK + r) * D;
  int d1 = (d + 1 < D) ? d + 1 : D - 1;
  f32x2 v;
  v.x = s[d];
  v.y = s[d1];
  dst[tid] = v;
}

__global__ __launch_bounds__(256, 4) void tensorcp_main(
    const float* __restrict__ xyz,
    const f32x2* __restrict__ CP,   // [3][DC][RANK] pairs
    const f32x2* __restrict__ FP,   // [3][DF][RANK] pairs
    const f32x2* __restrict__ UP,   // [3][DC][RANK] pairs
    const float* __restrict__ Wc,   // [64][64]
    const float* __restrict__ Wf,   // [64][64]
    float* __restrict__ out)        // [N][128] cat ++ [N] uncertainty
{
  // ONE staging buffer per wave, reused by all three phases.
  // 64 rows x 72 bf16 = 9216 B/wave -> 36864 B/block -> 4 blocks/CU.
  __shared__ __align__(16) unsigned short FS[4][64][72];

  const int lane = threadIdx.x & 63;
  const int wv = threadIdx.x >> 6;
  const int batch = blockIdx.x * 4 + wv;
  if (batch * 64 >= N_PTS) return;          // wave-uniform exit, no barriers used
  const int p0 = batch * 64;

  const int fcol = lane & 15;
  const int kg = lane >> 4;

  // ---------------- per-lane point parameters ----------------
  const int myp = p0 + lane;
  const float px = xyz[myp * 3 + 0];
  const float py = xyz[myp * 3 + 1];
  const float pz = xyz[myp * 3 + 2];

  float pc0 = px * (float)(DC - 1), pc1 = py * (float)(DC - 1), pc2 = pz * (float)(DC - 1);
  float pf0 = px * (float)(DF - 1), pf1 = py * (float)(DF - 1), pf2 = pz * (float)(DF - 1);
  int ic0 = min(max((int)floorf(pc0), 0), DC - 1);
  int ic1 = min(max((int)floorf(pc1), 0), DC - 1);
  int ic2 = min(max((int)floorf(pc2), 0), DC - 1);
  int if0 = min(max((int)floorf(pf0), 0), DF - 1);
  int if1 = min(max((int)floorf(pf1), 0), DF - 1);
  int if2 = min(max((int)floorf(pf2), 0), DF - 1);
  float wc0 = pc0 - (float)ic0, wc1 = pc1 - (float)ic1, wc2 = pc2 - (float)ic2;
  float wf0 = pf0 - (float)if0, wf1 = pf1 - (float)if1, wf2 = pf2 - (float)if2;

  unsigned short (&myF)[64][72] = FS[wv];

  const f32x2* CPx = CP;
  const f32x2* CPy = CP + DC * RANK;
  const f32x2* CPz = CP + 2 * DC * RANK;
  const f32x2* FPx = FP;
  const f32x2* FPy = FP + DF * RANK;
  const f32x2* FPz = FP + 2 * DF * RANK;
  const f32x2* UPx = UP;
  const f32x2* UPy = UP + DC * RANK;
  const f32x2* UPz = UP + 2 * DC * RANK;

  // ================= phase U: uncertainty =================
#pragma unroll 4
  for (int p = 0; p < 64; ++p) {
    const int s_ic0 = __builtin_amdgcn_readlane(ic0, p);
    const int s_ic1 = __builtin_amdgcn_readlane(ic1, p);
    const int s_ic2 = __builtin_amdgcn_readlane(ic2, p);
    const float s_wc0 = readlane_f(wc0, p);
    const float s_wc1 = readlane_f(wc1, p);
    const float s_wc2 = readlane_f(wc2, p);

    const f32x2 u0 = UPx[s_ic0 * RANK + lane];
    const f32x2 u1 = UPy[s_ic1 * RANK + lane];
    const f32x2 u2 = UPz[s_ic2 * RANK + lane];
    const float q0v = fmaf(s_wc0, u0.y - u0.x, u0.x);
    const float q1v = fmaf(s_wc1, u1.y - u1.x, u1.x);
    const float q2v = fmaf(s_wc2, u2.y - u2.x, u2.x);
    myF[p][lane] = f2bf(q0v * q1v * q2v);
  }
  asm volatile("s_waitcnt lgkmcnt(0)" ::: "memory");
  // per-lane row sum: lane = point
  float usum = 0.0f;
#pragma unroll
  for (int j = 0; j < 8; ++j) {
    short8 v = *(const short8*)&myF[lane][j * 8];
#pragma unroll
    for (int t = 0; t < 8; ++t) usum += bf2f((unsigned short)v[t]);
  }
  __builtin_nontemporal_store(usum, &out[(long long)N_PTS * 128 + p0 + lane]);

  // ================= phase C: coarse =================
#pragma unroll 4
  for (int p = 0; p < 64; ++p) {
    const int s_ic0 = __builtin_amdgcn_readlane(ic0, p);
    const int s_ic1 = __builtin_amdgcn_readlane(ic1, p);
    const int s_ic2 = __builtin_amdgcn_readlane(ic2, p);
    const float s_wc0 = readlane_f(wc0, p);
    const float s_wc1 = readlane_f(wc1, p);
    const float s_wc2 = readlane_f(wc2, p);

    const f32x2 c0 = CPx[s_ic0 * RANK + lane];
    const f32x2 c1 = CPy[s_ic1 * RANK + lane];
    const f32x2 c2 = CPz[s_ic2 * RANK + lane];
    const float a0v = fmaf(s_wc0, c0.y - c0.x, c0.x);
    const float a1v = fmaf(s_wc1, c1.y - c1.x, c1.x);
    const float a2v = fmaf(s_wc2, c2.y - c2.x, c2.x);
    myF[p][lane] = f2bf(a0v * a1v * a2v);
  }
  // B fragments for coarse W (loaded while staging drains)
  short8 Bc[8];   // index = k*4 + n
#pragma unroll
  for (int k = 0; k < 2; ++k) {
#pragma unroll
    for (int n = 0; n < 4; ++n) {
      const float* wp = Wc + (n * 16 + fcol) * 64 + k * 32 + kg * 8;
      f32x4 lo = *(const f32x4*)wp;
      f32x4 hi = *(const f32x4*)(wp + 4);
      short8 b;
      b[0] = (short)f2bf(lo[0]); b[1] = (short)f2bf(lo[1]);
      b[2] = (short)f2bf(lo[2]); b[3] = (short)f2bf(lo[3]);
      b[4] = (short)f2bf(hi[0]); b[5] = (short)f2bf(hi[1]);
      b[6] = (short)f2bf(hi[2]); b[7] = (short)f2bf(hi[3]);
      Bc[k * 4 + n] = b;
    }
  }
  asm volatile("s_waitcnt lgkmcnt(0)" ::: "memory");
  const long long rowbase = (long long)p0 * 128;
#pragma unroll
  for (int m = 0; m < 4; ++m) {
    const int prow = m * 16 + fcol;
    const short8 a0 = *(const short8*)&myF[prow][kg * 8];
    const short8 a1 = *(const short8*)&myF[prow][32 + kg * 8];
#pragma unroll
    for (int n = 0; n < 4; ++n) {
      f32x4 z = {0.f, 0.f, 0.f, 0.f};
      z = __builtin_amdgcn_mfma_f32_16x16x32_bf16(a0, Bc[n], z, 0, 0, 0);
      z = __builtin_amdgcn_mfma_f32_16x16x32_bf16(a1, Bc[4 + n], z, 0, 0, 0);
#pragma unroll
      for (int reg = 0; reg < 4; ++reg) {
        const long long ro = rowbase + (long long)(m * 16 + kg * 4 + reg) * 128;
        __builtin_nontemporal_store(z[reg], &out[ro + n * 16 + fcol]);
      }
    }
  }
  asm volatile("s_waitcnt lgkmcnt(0)" ::: "memory");  // A-frag reads landed before overwrite

  // ================= phase F: fine =================
#pragma unroll 4
  for (int p = 0; p < 64; ++p) {
    const int s_if0 = __builtin_amdgcn_readlane(if0, p);
    const int s_if1 = __builtin_amdgcn_readlane(if1, p);
    const int s_if2 = __builtin_amdgcn_readlane(if2, p);
    const float s_wf0 = readlane_f(wf0, p);
    const float s_wf1 = readlane_f(wf1, p);
    const float s_wf2 = readlane_f(wf2, p);

    const f32x2 g0 = FPx[s_if0 * RANK + lane];
    const f32x2 g1 = FPy[s_if1 * RANK + lane];
    const f32x2 g2 = FPz[s_if2 * RANK + lane];
    const float b0v = fmaf(s_wf0, g0.y - g0.x, g0.x);
    const float b1v = fmaf(s_wf1, g1.y - g1.x, g1.x);
    const float b2v = fmaf(s_wf2, g2.y - g2.x, g2.x);
    myF[p][lane] = f2bf(b0v * b1v * b2v);
  }
  short8 Bf[8];
#pragma unroll
  for (int k = 0; k < 2; ++k) {
#pragma unroll
    for (int n = 0; n < 4; ++n) {
      const float* wp = Wf + (n * 16 + fcol) * 64 + k * 32 + kg * 8;
      f32x4 lo = *(const f32x4*)wp;
      f32x4 hi = *(const f32x4*)(wp + 4);
      short8 b;
      b[0] = (short)f2bf(lo[0]); b[1] = (short)f2bf(lo[1]);
      b[2] = (short)f2bf(lo[2]); b[3] = (short)f2bf(lo[3]);
      b[4] = (short)f2bf(hi[0]); b[5] = (short)f2bf(hi[1]);
      b[6] = (short)f2bf(hi[2]); b[7] = (short)f2bf(hi[3]);
      Bf[k * 4 + n] = b;
    }
  }
  asm volatile("s_waitcnt lgkmcnt(0)" ::: "memory");
#pragma unroll
  for (int m = 0; m < 4; ++m) {
    const int prow = m * 16 + fcol;
    const short8 a0 = *(const short8*)&myF[prow][kg * 8];
    const short8 a1 = *(const short8*)&myF[prow][32 + kg * 8];
#pragma unroll
    for (int n = 0; n < 4; ++n) {
      f32x4 z = {0.f, 0.f, 0.f, 0.f};
      z = __builtin_amdgcn_mfma_f32_16x16x32_bf16(a0, Bf[n], z, 0, 0, 0);
      z = __builtin_amdgcn_mfma_f32_16x16x32_bf16(a1, Bf[4 + n], z, 0, 0, 0);
#pragma unroll
      for (int reg = 0; reg < 4; ++reg) {
        const long long ro = rowbase + (long long)(m * 16 + kg * 4 + reg) * 128;
        __builtin_nontemporal_store(z[reg], &out[ro + 64 + n * 16 + fcol]);
      }
    }
  }
}

extern "C" void kernel_launch(void* const* d_in, const int* in_sizes, int n_in,
                              void* d_out, int out_size, void* d_ws, size_t ws_size,
                              hipStream_t stream) {
  const float* xyz    = (const float*)d_in[0];
  const float* line_c = (const float*)d_in[1];
  const float* line_f = (const float*)d_in[2];
  const float* unc_l  = (const float*)d_in[3];
  const float* Wc     = (const float*)d_in[4];
  const float* Wf     = (const float*)d_in[5];
  float* out = (float*)d_out;

  f32x2* CP = (f32x2*)d_ws;            // 3*128*64 pairs
  f32x2* FP = CP + 3 * DC * RANK;      // 3*512*64 pairs
  f32x2* UP = FP + 3 * DF * RANK;      // 3*128*64 pairs

  const int tc = 3 * DC * RANK;  // 24576
  const int tf = 3 * DF * RANK;  // 98304
  build_pairs<<<(tc + 255) / 256, 256, 0, stream>>>(line_c, CP, DC);
  build_pairs<<<(tf + 255) / 256, 256, 0, stream>>>(line_f, FP, DF);
  build_pairs<<<(tc + 255) / 256, 256, 0, stream>>>(unc_l, UP, DC);

  const int nwaves = N_PTS / 64;            // 15625
  const int nblocks = (nwaves + 3) / 4;     // 3907
  tensorcp_main<<<nblocks, 256, 0, stream>>>(xyz, CP, FP, UP, Wc, Wf, out);
}